// Round 2
// baseline (181.017 us; speedup 1.0000x reference)
//
#include <hip/hip_runtime.h>

// Problem constants (from reference setup_inputs)
#define BB 8
#define QQ 30
#define DD 1500
#define EE 768
#define KK 11
#define WW 736      // (1500-30)/2 + 1
#define WIN 30
#define STR 2

// ---------------------------------------------------------------------------
// Kernel 1: per-row inverse norms (f64) for q (240 rows) and d (12000 rows)
// ---------------------------------------------------------------------------
__global__ __launch_bounds__(256) void skl_norms(
    const float* __restrict__ qe, const float* __restrict__ de,
    double* __restrict__ invq, double* __restrict__ invd)
{
    int row = blockIdx.x;
    const float* src;
    double* dst;
    if (row < BB * QQ) { src = qe + (size_t)row * EE; dst = invq + row; }
    else { int r = row - BB * QQ; src = de + (size_t)r * EE; dst = invd + r; }

    int tid = threadIdx.x;
    double ss = 0.0;
    for (int i = tid; i < EE; i += 256) { double v = (double)src[i]; ss += v * v; }
    #pragma unroll
    for (int off = 32; off >= 1; off >>= 1) ss += __shfl_down(ss, off);

    __shared__ double part[4];
    if ((tid & 63) == 0) part[tid >> 6] = ss;
    __syncthreads();
    if (tid == 0) {
        double t = part[0] + part[1] + part[2] + part[3];
        double n = sqrt(t);
        *dst = 1.0 / fmax(n, 1e-13);
    }
}

// ---------------------------------------------------------------------------
// Kernel 2: cosine matrix in f64: cos[b,q,d] = (q . d) * invq * invd
// block = (b, q-half of 15, d-tile of 64); 4 waves, wave-per-d GEMV
// ---------------------------------------------------------------------------
#define DTILE 64
#define NDT ((DD + DTILE - 1) / DTILE)   // 24

__global__ __launch_bounds__(256) void skl_cos(
    const float* __restrict__ qe,     // [8][30][768]
    const float* __restrict__ de,     // [8][1500][768]
    const double* __restrict__ invq,  // [240]
    const double* __restrict__ invd,  // [12000]
    double* __restrict__ cosm)        // [240][1500]
{
    __shared__ float qs[15 * EE];     // raw q rows, 45KB
    int bid = blockIdx.x;
    int dt = bid % NDT;
    int qh = (bid / NDT) & 1;
    int b  = bid / (2 * NDT);
    int qbase = b * QQ + qh * 15;
    int tid = threadIdx.x;

    for (int i = tid; i < 15 * EE; i += 256) {
        int q = i / EE; int e = i - q * EE;
        qs[i] = qe[(size_t)(qbase + q) * EE + e];
    }
    __syncthreads();

    int lane = tid & 63;
    int wid = tid >> 6;
    int d0 = dt * DTILE + wid * 16;
    for (int i = 0; i < 16; i++) {
        int d = d0 + i;
        if (d >= DD) break;                 // wave-uniform
        const float* drow = de + ((size_t)b * DD + d) * EE;
        float dr[12];
        #pragma unroll
        for (int j = 0; j < 12; j++) dr[j] = drow[64 * j + lane];
        double iv = invd[b * DD + d];
        for (int q = 0; q < 15; q++) {
            const float* qrow = qs + q * EE;
            double p = 0.0;
            #pragma unroll
            for (int j = 0; j < 12; j++)
                p += (double)dr[j] * (double)qrow[64 * j + lane];
            #pragma unroll
            for (int off = 32; off >= 1; off >>= 1) p += __shfl_xor(p, off);
            if (lane == 0)
                cosm[(size_t)(qbase + q) * DD + d] = p * invq[qbase + q] * iv;
        }
    }
}

// ---------------------------------------------------------------------------
// Kernel 3: RBF kernels -> windowed sums -> saturation -> dense_w (all f64)
// block per (b,q,chunk of 256 windows): 720 blocks, 1 window/thread
// ---------------------------------------------------------------------------
#define DCH 544    // max d-extent a chunk needs (2*255+29+1 = 540, padded)

__global__ __launch_bounds__(256) void skl_windows(
    const double* __restrict__ cosm,   // [240][1500]
    const float* __restrict__ dmask,   // [8][1500]
    const float* __restrict__ qmask,   // [8][30]
    const float* __restrict__ qidfs,   // [240]
    const float* __restrict__ mu,      // [11]
    const float* __restrict__ sigma,   // [11]
    const float* __restrict__ w1, const float* __restrict__ b1,
    const float* __restrict__ w2, const float* __restrict__ b2,
    const float* __restrict__ w3, const float* __restrict__ b3,
    const float* __restrict__ dw,      // [11]
    double* __restrict__ pscore)       // [240][736]
{
    __shared__ double vf[DCH];
    __shared__ double sacc[DCH];

    int bid = blockIdx.x;     // 0..719
    int c  = bid % 3;
    int bq = bid / 3;         // 0..239
    int b  = bq / QQ;
    int tid = threadIdx.x;

    int dbase = 512 * c;
    int dcount = min(540, DD - dbase);
    int w = c * 256 + tid;
    bool active = (w < WW);

    for (int i = tid; i < DCH; i += 256) sacc[i] = 0.0;

    const double* crow = cosm + (size_t)bq * DD + dbase;
    const float* dm = dmask + (size_t)b * DD + dbase;

    double pk[KK];
    for (int k = 0; k < KK; k++) {
        double muk = (double)mu[k];
        double sk  = (double)sigma[k];
        double i2s = 1.0 / (2.0 * sk * sk);
        __syncthreads();   // protect vf from previous pass readers + sacc init
        for (int i = tid; i < dcount; i += 256) {
            double diff = crow[i] - muk;
            double val = exp(-diff * diff * i2s) * (double)dm[i];
            vf[i] = val;
            sacc[i] += val;
        }
        __syncthreads();
        double s = 0.0;
        if (active) {
            int dl = 2 * tid;
            #pragma unroll
            for (int j = 0; j < WIN; j++) s += vf[dl + j];
        }
        pk[k] = s;
    }

    if (active) {
        int dl = 2 * tid;
        int len = 0;
        #pragma unroll
        for (int j = 0; j < WIN; j++) len += (sacc[dl + j] != 0.0) ? 1 : 0;

        double idf = fmax((double)qidfs[bq], 0.0);
        double lenf = (double)len;
        double sat1 = idf * (double)w1[0] + lenf * (double)w1[1] + (double)b1[0];
        double sat2 = 1.0 / (idf * (double)w2[0] + lenf * (double)w2[1] + (double)b2[0]);
        double sat3 = idf * (double)w3[0] + lenf * (double)w3[1] + (double)b3[0];
        double qm = (double)qmask[bq];
        double mult = qm * (len > 0 ? 1.0 : 0.0);

        double acc = 0.0;
        #pragma unroll
        for (int k = 0; k < KK; k++) {
            double x = fmax(pk[k], 1e-10);
            double sp = sat1 * pow(x, sat2) - sat3;
            acc += sp * (double)dw[k];
        }
        pscore[(size_t)bq * WW + w] = acc * mult;
    }
}

// ---------------------------------------------------------------------------
// Kernel 4: per batch: sum over q, sentinel, top-3 argmax + pooling, gather
// one wave (64 threads) per batch, all f64
// ---------------------------------------------------------------------------
__global__ __launch_bounds__(64) void skl_topk(
    const double* __restrict__ pscore,  // [240][736]
    const float* __restrict__ chunk,    // [15]
    float* __restrict__ out)            // [8]
{
    __shared__ double s0[WW];
    int b = blockIdx.x;
    int lane = threadIdx.x;

    double m[12];
    #pragma unroll
    for (int r = 0; r < 12; r++) {
        int w = lane + 64 * r;
        double v = -1.7e308;
        if (w < WW) {
            double s = 0.0;
            for (int q = 0; q < QQ; q++) s += pscore[(size_t)(b * QQ + q) * WW + w];
            v = (s == 0.0) ? -9900.0 : s;
            s0[w] = v;
        }
        m[r] = v;
    }
    __syncthreads();

    int best[3];
    for (int c = 0; c < 3; c++) {
        double bv = -1.7e308;
        int bi = 1 << 30;
        #pragma unroll
        for (int r = 0; r < 12; r++) {
            int w = lane + 64 * r;
            if (w < WW && m[r] > bv) { bv = m[r]; bi = w; }
        }
        #pragma unroll
        for (int off = 32; off >= 1; off >>= 1) {
            double ov = __shfl_down(bv, off);
            int oi = __shfl_down(bi, off);
            if (ov > bv || (ov == bv && oi < bi)) { bv = ov; bi = oi; }
        }
        bi = __shfl(bi, 0);
        best[c] = bi;
        double pen = -10001.0 - (double)c;
        #pragma unroll
        for (int r = 0; r < 12; r++) {
            int w = lane + 64 * r;
            int dd = w - bi; if (dd < 0) dd = -dd;
            if (w < WW && dd < 15) m[r] = pen;
        }
    }

    double contrib = 0.0;
    if (lane < 15) {
        int c = lane % 3;
        int g = lane / 3;
        const int offs[5] = {0, -1, 1, -2, 2};
        int nb = best[c] + offs[g];
        nb = min(max(nb, 0), WW - 1);
        double v = s0[nb];
        if (v <= -9900.0) v = 0.0;
        contrib = v * (double)chunk[lane];
    }
    #pragma unroll
    for (int off = 32; off >= 1; off >>= 1) contrib += __shfl_down(contrib, off);
    if (lane == 0) out[b] = (float)contrib;
}

// ---------------------------------------------------------------------------
extern "C" void kernel_launch(void* const* d_in, const int* in_sizes, int n_in,
                              void* d_out, int out_size, void* d_ws, size_t ws_size,
                              hipStream_t stream) {
    const float* qe    = (const float*)d_in[0];   // (8,30,768)
    const float* de    = (const float*)d_in[1];   // (8,1500,768)
    const float* qmask = (const float*)d_in[2];   // (8,30)
    const float* dmask = (const float*)d_in[3];   // (8,1500)
    const float* qidfs = (const float*)d_in[4];   // (8,30,1)
    // d_in[5] = document_idfs (unused by reference)
    const float* mu    = (const float*)d_in[6];   // (11,)
    const float* sigma = (const float*)d_in[7];   // (11,)
    const float* w1    = (const float*)d_in[8];
    const float* b1    = (const float*)d_in[9];
    const float* w2    = (const float*)d_in[10];
    const float* b2    = (const float*)d_in[11];
    const float* w3    = (const float*)d_in[12];
    const float* b3    = (const float*)d_in[13];
    const float* dw    = (const float*)d_in[14];  // (1,11)
    const float* chunk = (const float*)d_in[15];  // (1,15)
    float* out = (float*)d_out;

    double* wsd = (double*)d_ws;
    double* invq   = wsd;            // 240    (reserve 256)
    double* invd   = wsd + 256;      // 12000  (reserve to 12288)
    double* cosm   = wsd + 12288;    // 240*1500 = 360000 (ends 372288)
    double* pscore = wsd + 372288;   // 240*736 = 176640  (ends 548928) ~4.4MB

    skl_norms<<<BB * QQ + BB * DD, 256, 0, stream>>>(qe, de, invq, invd);
    skl_cos<<<BB * 2 * NDT, 256, 0, stream>>>(qe, de, invq, invd, cosm);
    skl_windows<<<BB * QQ * 3, 256, 0, stream>>>(cosm, dmask, qmask, qidfs, mu, sigma,
                                                 w1, b1, w2, b2, w3, b3, dw, pscore);
    skl_topk<<<BB, 64, 0, stream>>>(pscore, chunk, out);
}

// Round 3
// 100.420 us; speedup vs baseline: 1.8026x; 1.8026x over previous
//
#include <hip/hip_runtime.h>

// Problem constants (from reference setup_inputs)
#define BB 8
#define QQ 30
#define DD 1500
#define EE 768
#define KK 11
#define WW 736      // (1500-30)/2 + 1
#define WIN 30
#define STR 2

// ---------------------------------------------------------------------------
// Kernel 1: per-row inverse norms (f32), one wave per row, 4 rows per block
// ---------------------------------------------------------------------------
__global__ __launch_bounds__(256) void skl_norms(
    const float* __restrict__ qe, const float* __restrict__ de,
    float* __restrict__ invq, float* __restrict__ invd)
{
    int wid = threadIdx.x >> 6, lane = threadIdx.x & 63;
    int row = blockIdx.x * 4 + wid;
    if (row >= BB * QQ + BB * DD) return;
    const float* src;
    float* dst;
    if (row < BB * QQ) { src = qe + (size_t)row * EE; dst = invq + row; }
    else { int r = row - BB * QQ; src = de + (size_t)r * EE; dst = invd + r; }

    const float4* p = (const float4*)src;   // 192 float4 per row
    float ss = 0.f;
    #pragma unroll
    for (int k = 0; k < 3; k++) {
        float4 v = p[lane + 64 * k];
        ss += v.x * v.x + v.y * v.y + v.z * v.z + v.w * v.w;
    }
    #pragma unroll
    for (int off = 32; off >= 1; off >>= 1) ss += __shfl_down(ss, off);
    if (lane == 0) *dst = 1.f / fmaxf(sqrtf(ss), 1e-13f);
}

// ---------------------------------------------------------------------------
// Kernel 2: cosine matrix f32 GEMM-style
// block: 16 q-rows (15 real + pad) x 64 d-rows; E-chunks of 128 in LDS;
// each thread owns a 2x2 (q,d) output block -> 4 FMA per ds_read_b128
// ---------------------------------------------------------------------------
#define EC 128
#define QT 16
#define DT 64
#define NDT ((DD + DT - 1) / DT)     // 24
#define DSTRIDE (EC + 4)             // 132 f32: odd float4-slot stride

__global__ __launch_bounds__(256) void skl_cos(
    const float* __restrict__ qe,    // [8][30][768]
    const float* __restrict__ de,    // [8][1500][768]
    const float* __restrict__ invq,  // [240]
    const float* __restrict__ invd,  // [12000]
    float* __restrict__ cosm)        // [240][1500]
{
    __shared__ float qs[QT * DSTRIDE];   // 8.25 KB
    __shared__ float ds[DT * DSTRIDE];   // 33 KB
    int dt = blockIdx.x;       // 0..23
    int qh = blockIdx.y;       // 0..1
    int b  = blockIdx.z;       // 0..7
    int qbase = b * QQ + qh * 15;
    int dbase = dt * DT;
    int tid = threadIdx.x;

    int qgrp = tid >> 5;       // 0..7  -> q rows {qgrp, qgrp+8}
    int dgrp = tid & 31;       // 0..31 -> d rows {dgrp, dgrp+32}

    float a00 = 0.f, a01 = 0.f, a10 = 0.f, a11 = 0.f;

    for (int ch = 0; ch < 6; ch++) {
        int e0 = ch * EC;
        __syncthreads();   // previous chunk's readers done
        // stage q tile: 16 rows x 32 float4 = 512; 2 per thread
        #pragma unroll
        for (int k = 0; k < 2; k++) {
            int f = tid + k * 256;
            int row = f >> 5, col4 = f & 31;
            float4 v = make_float4(0.f, 0.f, 0.f, 0.f);
            if (row < 15)
                v = *(const float4*)(qe + (size_t)(qbase + row) * EE + e0 + col4 * 4);
            *(float4*)&qs[row * DSTRIDE + col4 * 4] = v;
        }
        // stage d tile: 64 rows x 32 float4 = 2048; 8 per thread
        #pragma unroll
        for (int k = 0; k < 8; k++) {
            int f = tid + k * 256;
            int row = f >> 5, col4 = f & 31;
            int d = dbase + row;
            float4 v = make_float4(0.f, 0.f, 0.f, 0.f);
            if (d < DD)
                v = *(const float4*)(de + ((size_t)b * DD + d) * EE + e0 + col4 * 4);
            *(float4*)&ds[row * DSTRIDE + col4 * 4] = v;
        }
        __syncthreads();
        const float* q0p = &qs[qgrp * DSTRIDE];
        const float* q1p = &qs[(qgrp + 8) * DSTRIDE];
        const float* d0p = &ds[dgrp * DSTRIDE];
        const float* d1p = &ds[(dgrp + 32) * DSTRIDE];
        #pragma unroll 8
        for (int e4 = 0; e4 < 32; e4++) {
            float4 q0 = *(const float4*)&q0p[e4 * 4];
            float4 q1 = *(const float4*)&q1p[e4 * 4];
            float4 d0 = *(const float4*)&d0p[e4 * 4];
            float4 d1 = *(const float4*)&d1p[e4 * 4];
            a00 += q0.x * d0.x + q0.y * d0.y + q0.z * d0.z + q0.w * d0.w;
            a01 += q0.x * d1.x + q0.y * d1.y + q0.z * d1.z + q0.w * d1.w;
            a10 += q1.x * d0.x + q1.y * d0.y + q1.z * d0.z + q1.w * d0.w;
            a11 += q1.x * d1.x + q1.y * d1.y + q1.z * d1.z + q1.w * d1.w;
        }
    }

    int r0 = qgrp, r1 = qgrp + 8;
    int d0 = dbase + dgrp, d1 = d0 + 32;
    float iq0 = invq[qbase + r0];
    float iq1 = (r1 < 15) ? invq[qbase + r1] : 0.f;
    if (d0 < DD) {
        float iv = invd[b * DD + d0];
        cosm[(size_t)(qbase + r0) * DD + d0] = a00 * iq0 * iv;
        if (r1 < 15) cosm[(size_t)(qbase + r1) * DD + d0] = a10 * iq1 * iv;
    }
    if (d1 < DD) {
        float iv = invd[b * DD + d1];
        cosm[(size_t)(qbase + r0) * DD + d1] = a01 * iq0 * iv;
        if (r1 < 15) cosm[(size_t)(qbase + r1) * DD + d1] = a11 * iq1 * iv;
    }
}

// ---------------------------------------------------------------------------
// Kernel 3: RBF kernels (f64 exp, f32 store) -> windowed sums (f64) ->
// saturation (f64) -> dense_w. One barrier. Block per (b,q,chunk of 256 w).
// ---------------------------------------------------------------------------
#define DCH 544    // max d-extent a chunk needs (2*255+29+1 = 540, padded)

__global__ __launch_bounds__(256) void skl_windows(
    const float* __restrict__ cosm,    // [240][1500]
    const float* __restrict__ dmask,   // [8][1500]
    const float* __restrict__ qmask,   // [8][30]
    const float* __restrict__ qidfs,   // [240]
    const float* __restrict__ mu,      // [11]
    const float* __restrict__ sigma,   // [11]
    const float* __restrict__ w1, const float* __restrict__ b1,
    const float* __restrict__ w2, const float* __restrict__ b2,
    const float* __restrict__ w3, const float* __restrict__ b3,
    const float* __restrict__ dw,      // [11]
    double* __restrict__ pscore)       // [240][736]
{
    __shared__ float vf[KK][DCH];      // 23.9 KB
    __shared__ float fl[DCH];          // length flags

    int bid = blockIdx.x;     // 0..719
    int c  = bid % 3;
    int bq = bid / 3;         // 0..239
    int b  = bq / QQ;
    int tid = threadIdx.x;

    int dbase = 512 * c;
    int dcount = min(540, DD - dbase);
    int w = c * 256 + tid;
    bool active = (w < WW);

    const float* crow = cosm + (size_t)bq * DD + dbase;
    const float* dm = dmask + (size_t)b * DD + dbase;

    double muL[KK], i2s[KK];
    #pragma unroll
    for (int k = 0; k < KK; k++) {
        muL[k] = (double)mu[k];
        double s = (double)sigma[k];
        i2s[k] = 1.0 / (2.0 * s * s);
    }

    // phase 1: all 11 RBF values per d (f64 exp), f32 store; f64 flag
    for (int i = tid; i < dcount; i += 256) {
        double cc = (double)crow[i];
        double m = (double)dm[i];
        double s = 0.0;
        #pragma unroll
        for (int k = 0; k < KK; k++) {
            double diff = cc - muL[k];
            double val = exp(-diff * diff * i2s[k]) * m;
            s += val;
            vf[k][i] = (float)val;
        }
        fl[i] = (s != 0.0) ? 1.f : 0.f;
    }
    __syncthreads();

    // phase 2: per-window sums + saturation + dense_w
    if (active) {
        int dl = 2 * tid;
        double pk[KK];
        #pragma unroll
        for (int k = 0; k < KK; k++) pk[k] = 0.0;
        int len = 0;
        for (int j = 0; j < WIN; j++) {
            len += (fl[dl + j] != 0.f) ? 1 : 0;
            #pragma unroll
            for (int k = 0; k < KK; k++) pk[k] += (double)vf[k][dl + j];
        }
        double idf = fmax((double)qidfs[bq], 0.0);
        double lenf = (double)len;
        double sat1 = idf * (double)w1[0] + lenf * (double)w1[1] + (double)b1[0];
        double sat2 = 1.0 / (idf * (double)w2[0] + lenf * (double)w2[1] + (double)b2[0]);
        double sat3 = idf * (double)w3[0] + lenf * (double)w3[1] + (double)b3[0];
        double mult = (double)qmask[bq] * (len > 0 ? 1.0 : 0.0);

        double acc = 0.0;
        #pragma unroll
        for (int k = 0; k < KK; k++) {
            double x = fmax(pk[k], 1e-10);
            double sp = sat1 * pow(x, sat2) - sat3;
            acc += sp * (double)dw[k];
        }
        pscore[(size_t)bq * WW + w] = acc * mult;
    }
}

// ---------------------------------------------------------------------------
// Kernel 4: per batch: sum over q, sentinel, top-3 argmax + pooling, gather
// one wave (64 threads) per batch, all f64
// ---------------------------------------------------------------------------
__global__ __launch_bounds__(64) void skl_topk(
    const double* __restrict__ pscore,  // [240][736]
    const float* __restrict__ chunk,    // [15]
    float* __restrict__ out)            // [8]
{
    __shared__ double s0[WW];
    int b = blockIdx.x;
    int lane = threadIdx.x;

    double m[12];
    #pragma unroll
    for (int r = 0; r < 12; r++) {
        int w = lane + 64 * r;
        double v = -1.7e308;
        if (w < WW) {
            double s = 0.0;
            for (int q = 0; q < QQ; q++) s += pscore[(size_t)(b * QQ + q) * WW + w];
            v = (s == 0.0) ? -9900.0 : s;
            s0[w] = v;
        }
        m[r] = v;
    }
    __syncthreads();

    int best[3];
    for (int c = 0; c < 3; c++) {
        double bv = -1.7e308;
        int bi = 1 << 30;
        #pragma unroll
        for (int r = 0; r < 12; r++) {
            int w = lane + 64 * r;
            if (w < WW && m[r] > bv) { bv = m[r]; bi = w; }
        }
        #pragma unroll
        for (int off = 32; off >= 1; off >>= 1) {
            double ov = __shfl_down(bv, off);
            int oi = __shfl_down(bi, off);
            if (ov > bv || (ov == bv && oi < bi)) { bv = ov; bi = oi; }
        }
        bi = __shfl(bi, 0);
        best[c] = bi;
        double pen = -10001.0 - (double)c;
        #pragma unroll
        for (int r = 0; r < 12; r++) {
            int w = lane + 64 * r;
            int dd = w - bi; if (dd < 0) dd = -dd;
            if (w < WW && dd < 15) m[r] = pen;
        }
    }

    double contrib = 0.0;
    if (lane < 15) {
        int c = lane % 3;
        int g = lane / 3;
        const int offs[5] = {0, -1, 1, -2, 2};
        int nb = best[c] + offs[g];
        nb = min(max(nb, 0), WW - 1);
        double v = s0[nb];
        if (v <= -9900.0) v = 0.0;
        contrib = v * (double)chunk[lane];
    }
    #pragma unroll
    for (int off = 32; off >= 1; off >>= 1) contrib += __shfl_down(contrib, off);
    if (lane == 0) out[b] = (float)contrib;
}

// ---------------------------------------------------------------------------
extern "C" void kernel_launch(void* const* d_in, const int* in_sizes, int n_in,
                              void* d_out, int out_size, void* d_ws, size_t ws_size,
                              hipStream_t stream) {
    const float* qe    = (const float*)d_in[0];   // (8,30,768)
    const float* de    = (const float*)d_in[1];   // (8,1500,768)
    const float* qmask = (const float*)d_in[2];   // (8,30)
    const float* dmask = (const float*)d_in[3];   // (8,1500)
    const float* qidfs = (const float*)d_in[4];   // (8,30,1)
    // d_in[5] = document_idfs (unused by reference)
    const float* mu    = (const float*)d_in[6];   // (11,)
    const float* sigma = (const float*)d_in[7];   // (11,)
    const float* w1    = (const float*)d_in[8];
    const float* b1    = (const float*)d_in[9];
    const float* w2    = (const float*)d_in[10];
    const float* b2    = (const float*)d_in[11];
    const float* w3    = (const float*)d_in[12];
    const float* b3    = (const float*)d_in[13];
    const float* dw    = (const float*)d_in[14];  // (1,11)
    const float* chunk = (const float*)d_in[15];  // (1,15)
    float* out = (float*)d_out;

    // workspace layout: pscore (f64) first for alignment, then f32 arrays
    double* pscore = (double*)d_ws;                       // 240*736 = 176640 f64
    float* fbase = (float*)((char*)d_ws + (size_t)176640 * 8);
    float* invq = fbase;            // 240   (reserve 256)
    float* invd = fbase + 256;      // 12000 (reserve to 12544)
    float* cosm = fbase + 12544;    // 360000  -> total ~2.9 MB

    skl_norms<<<(BB * QQ + BB * DD + 3) / 4, 256, 0, stream>>>(qe, de, invq, invd);
    skl_cos<<<dim3(NDT, 2, BB), 256, 0, stream>>>(qe, de, invq, invd, cosm);
    skl_windows<<<BB * QQ * 3, 256, 0, stream>>>(cosm, dmask, qmask, qidfs, mu, sigma,
                                                 w1, b1, w2, b2, w3, b3, dw, pscore);
    skl_topk<<<BB, 64, 0, stream>>>(pscore, chunk, out);
}

// Round 4
// 92.268 us; speedup vs baseline: 1.9619x; 1.0884x over previous
//
#include <hip/hip_runtime.h>

// Problem constants (from reference setup_inputs)
#define BB 8
#define QQ 30
#define DD 1500
#define EE 768
#define KK 11
#define WW 736      // (1500-30)/2 + 1
#define WIN 30
#define STR 2

#define ESPL 8      // E split count
#define ECH 96      // e per split (24 float4)

// ---------------------------------------------------------------------------
// Kernel 1: normalize q rows (240 rows): qn = qe / max(||qe||, 1e-13)
// ---------------------------------------------------------------------------
__global__ __launch_bounds__(256) void skl_normq(
    const float* __restrict__ qe, float* __restrict__ qn)
{
    int wid = threadIdx.x >> 6, lane = threadIdx.x & 63;
    int row = blockIdx.x * 4 + wid;
    if (row >= BB * QQ) return;
    const float4* p = (const float4*)(qe + (size_t)row * EE);
    float4 v[3];
    float ss = 0.f;
    #pragma unroll
    for (int k = 0; k < 3; k++) {
        v[k] = p[lane + 64 * k];
        ss += v[k].x * v[k].x + v[k].y * v[k].y + v[k].z * v[k].z + v[k].w * v[k].w;
    }
    #pragma unroll
    for (int off = 32; off >= 1; off >>= 1) ss += __shfl_xor(ss, off);
    float inv = 1.f / fmaxf(sqrtf(ss), 1e-13f);
    float4* o = (float4*)(qn + (size_t)row * EE);
    #pragma unroll
    for (int k = 0; k < 3; k++) {
        float4 w = v[k];
        w.x *= inv; w.y *= inv; w.z *= inv; w.w *= inv;
        o[lane + 64 * k] = w;
    }
}

// ---------------------------------------------------------------------------
// Kernel 2: cos partials. Thread owns one d-row segment (96 e), streams it
// from global (L1-friendly), accumulates 30 q dot-partials with the q operand
// read via block-uniform (scalar) loads. No LDS, no barriers, no shuffles.
// Also accumulates per-d sum-of-squares partial (invd folded downstream).
// grid = (6 d-supertiles of 256, 8 e-chunks, 8 batches)
// ---------------------------------------------------------------------------
__global__ __launch_bounds__(256) void skl_cos(
    const float* __restrict__ de,     // [8][1500][768]
    const float* __restrict__ qn,     // [240][768] normalized
    float* __restrict__ cpart,        // [8][240][1500]
    float* __restrict__ dssq)         // [8][8][1500]
{
    int tid = threadIdx.x;
    int dsup = blockIdx.x;   // 0..5
    int ec   = blockIdx.y;   // 0..7
    int b    = blockIdx.z;   // 0..7
    int d = dsup * 256 + tid;
    int dld = min(d, DD - 1);
    const float4* drow = (const float4*)(de + ((size_t)b * DD + dld) * EE + ec * ECH);
    const float* qbase = qn + (size_t)b * QQ * EE + ec * ECH;

    float acc[QQ];
    #pragma unroll
    for (int q = 0; q < QQ; q++) acc[q] = 0.f;
    float ssq = 0.f;

    #pragma unroll 2
    for (int e4 = 0; e4 < ECH / 4; e4++) {
        float4 dv = drow[e4];
        ssq += dv.x * dv.x + dv.y * dv.y + dv.z * dv.z + dv.w * dv.w;
        #pragma unroll
        for (int q = 0; q < QQ; q++) {
            const float4 qv = *(const float4*)(qbase + q * EE + e4 * 4);
            acc[q] += dv.x * qv.x + dv.y * qv.y + dv.z * qv.z + dv.w * qv.w;
        }
    }

    if (d < DD) {
        float* op = cpart + ((size_t)ec * BB * QQ + (size_t)b * QQ) * DD + d;
        #pragma unroll
        for (int q = 0; q < QQ; q++) op[(size_t)q * DD] = acc[q];
        dssq[((size_t)ec * BB + b) * DD + d] = ssq;
    }
}

// ---------------------------------------------------------------------------
// Kernel 3: sum cos partials, apply invd (rsqrt of ssq partials, inline),
// RBF kernels (f32 __expf) -> windowed sums (f64) -> saturation (f64) ->
// dense_w. Block per (b,q,chunk of 256 windows).
// ---------------------------------------------------------------------------
#define DCH 544    // max d-extent a chunk needs (2*255+29+1 = 540, padded)

__global__ __launch_bounds__(256) void skl_windows(
    const float* __restrict__ cpart,   // [8][240][1500]
    const float* __restrict__ dssq,    // [8][8][1500]
    const float* __restrict__ dmask,   // [8][1500]
    const float* __restrict__ qmask,   // [8][30]
    const float* __restrict__ qidfs,   // [240]
    const float* __restrict__ mu,      // [11]
    const float* __restrict__ sigma,   // [11]
    const float* __restrict__ w1, const float* __restrict__ b1,
    const float* __restrict__ w2, const float* __restrict__ b2,
    const float* __restrict__ w3, const float* __restrict__ b3,
    const float* __restrict__ dw,      // [11]
    float* __restrict__ pscore)        // [240][736]
{
    __shared__ float vf[KK][DCH];      // 23.9 KB
    __shared__ float fl[DCH];

    int bid = blockIdx.x;     // 0..719
    int c  = bid % 3;
    int bq = bid / 3;         // 0..239
    int b  = bq / QQ;
    int tid = threadIdx.x;

    int dbase = 512 * c;
    int dcount = min(540, DD - dbase);
    int w = c * 256 + tid;
    bool active = (w < WW);

    float muL[KK], i2s[KK];
    #pragma unroll
    for (int k = 0; k < KK; k++) {
        muL[k] = mu[k];
        float s = sigma[k];
        i2s[k] = 1.f / (2.f * s * s);
    }
    const float* dm = dmask + (size_t)b * DD + dbase;

    // phase 1: sum e-partials, invd, mask, 11 RBF values per d
    for (int i = tid; i < dcount; i += 256) {
        int dg = dbase + i;
        float s = 0.f, sq = 0.f;
        #pragma unroll
        for (int p = 0; p < ESPL; p++) {
            s  += cpart[((size_t)p * BB * QQ + bq) * DD + dg];
            sq += dssq[((size_t)p * BB + b) * DD + dg];
        }
        float invd = 1.f / fmaxf(sqrtf(sq), 1e-13f);
        float cc = s * invd;
        float m = dm[i];
        float ssum = 0.f;
        #pragma unroll
        for (int k = 0; k < KK; k++) {
            float diff = cc - muL[k];
            float val = __expf(-diff * diff * i2s[k]) * m;
            ssum += val;
            vf[k][i] = val;
        }
        fl[i] = (ssum != 0.f) ? 1.f : 0.f;
    }
    __syncthreads();

    // phase 2: per-window sums + saturation + dense_w
    if (active) {
        int dl = 2 * tid;
        double pk[KK];
        #pragma unroll
        for (int k = 0; k < KK; k++) pk[k] = 0.0;
        int len = 0;
        for (int j = 0; j < WIN; j++) {
            len += (fl[dl + j] != 0.f) ? 1 : 0;
            #pragma unroll
            for (int k = 0; k < KK; k++) pk[k] += (double)vf[k][dl + j];
        }
        double idf = fmax((double)qidfs[bq], 0.0);
        double lenf = (double)len;
        double sat1 = idf * (double)w1[0] + lenf * (double)w1[1] + (double)b1[0];
        double sat2 = 1.0 / (idf * (double)w2[0] + lenf * (double)w2[1] + (double)b2[0]);
        double sat3 = idf * (double)w3[0] + lenf * (double)w3[1] + (double)b3[0];
        double mult = (double)qmask[bq] * (len > 0 ? 1.0 : 0.0);

        double acc = 0.0;
        #pragma unroll
        for (int k = 0; k < KK; k++) {
            double x = fmax(pk[k], 1e-10);
            double sp = sat1 * pow(x, sat2) - sat3;
            acc += sp * (double)dw[k];
        }
        pscore[(size_t)bq * WW + w] = (float)(acc * mult);
    }
}

// ---------------------------------------------------------------------------
// Kernel 4: per batch: sum over q (256 threads), then single-wave top-3
// argmax + pooling + gather.
// ---------------------------------------------------------------------------
__global__ __launch_bounds__(256) void skl_topk(
    const float* __restrict__ pscore,  // [240][736]
    const float* __restrict__ chunk,   // [15]
    float* __restrict__ out)           // [8]
{
    __shared__ float s0[WW];
    int b = blockIdx.x;
    int tid = threadIdx.x;

    for (int w = tid; w < WW; w += 256) {
        float s = 0.f;
        for (int q = 0; q < QQ; q++) s += pscore[(size_t)(b * QQ + q) * WW + w];
        s0[w] = (s == 0.f) ? -9900.f : s;
    }
    __syncthreads();

    if (tid < 64) {
        int lane = tid;
        float m[12];
        #pragma unroll
        for (int r = 0; r < 12; r++) {
            int w = lane + 64 * r;
            m[r] = (w < WW) ? s0[w] : -3.3e38f;
        }

        int best[3];
        for (int c = 0; c < 3; c++) {
            float bv = -3.3e38f;
            int bi = 1 << 30;
            #pragma unroll
            for (int r = 0; r < 12; r++) {
                int w = lane + 64 * r;
                if (w < WW && m[r] > bv) { bv = m[r]; bi = w; }
            }
            #pragma unroll
            for (int off = 32; off >= 1; off >>= 1) {
                float ov = __shfl_down(bv, off);
                int oi = __shfl_down(bi, off);
                if (ov > bv || (ov == bv && oi < bi)) { bv = ov; bi = oi; }
            }
            bi = __shfl(bi, 0);
            best[c] = bi;
            float pen = -10001.f - (float)c;
            #pragma unroll
            for (int r = 0; r < 12; r++) {
                int w = lane + 64 * r;
                int dd = w - bi; if (dd < 0) dd = -dd;
                if (w < WW && dd < 15) m[r] = pen;
            }
        }

        float contrib = 0.f;
        if (lane < 15) {
            int c = lane % 3;
            int g = lane / 3;
            const int offs[5] = {0, -1, 1, -2, 2};
            int nb = best[c] + offs[g];
            nb = min(max(nb, 0), WW - 1);
            float v = s0[nb];
            if (v <= -9900.f) v = 0.f;
            contrib = v * chunk[lane];
        }
        #pragma unroll
        for (int off = 32; off >= 1; off >>= 1) contrib += __shfl_down(contrib, off);
        if (lane == 0) out[b] = contrib;
    }
}

// ---------------------------------------------------------------------------
extern "C" void kernel_launch(void* const* d_in, const int* in_sizes, int n_in,
                              void* d_out, int out_size, void* d_ws, size_t ws_size,
                              hipStream_t stream) {
    const float* qe    = (const float*)d_in[0];   // (8,30,768)
    const float* de    = (const float*)d_in[1];   // (8,1500,768)
    const float* qmask = (const float*)d_in[2];   // (8,30)
    const float* dmask = (const float*)d_in[3];   // (8,1500)
    const float* qidfs = (const float*)d_in[4];   // (8,30,1)
    // d_in[5] = document_idfs (unused by reference)
    const float* mu    = (const float*)d_in[6];   // (11,)
    const float* sigma = (const float*)d_in[7];   // (11,)
    const float* w1    = (const float*)d_in[8];
    const float* b1    = (const float*)d_in[9];
    const float* w2    = (const float*)d_in[10];
    const float* b2    = (const float*)d_in[11];
    const float* w3    = (const float*)d_in[12];
    const float* b3    = (const float*)d_in[13];
    const float* dw    = (const float*)d_in[14];  // (1,11)
    const float* chunk = (const float*)d_in[15];  // (1,15)
    float* out = (float*)d_out;

    float* ws = (float*)d_ws;
    float* cpart  = ws;                    // 8*240*1500 = 2,880,000
    float* dssq   = ws + 2880000;          // 8*8*1500   =    96,000
    float* qn     = ws + 2976000;          // 240*768    =   184,320
    float* pscore = ws + 3160320;          // 240*736    =   176,640  (~13.3MB)

    skl_normq<<<60, 256, 0, stream>>>(qe, qn);
    skl_cos<<<dim3(6, ESPL, BB), 256, 0, stream>>>(de, qn, cpart, dssq);
    skl_windows<<<BB * QQ * 3, 256, 0, stream>>>(cpart, dssq, dmask, qmask, qidfs,
                                                 mu, sigma, w1, b1, w2, b2, w3, b3,
                                                 dw, pscore);
    skl_topk<<<BB, 256, 0, stream>>>(pscore, chunk, out);
}

// Round 6
// 61.434 us; speedup vs baseline: 2.9466x; 1.5019x over previous
//
#include <hip/hip_runtime.h>

// Problem constants (from reference setup_inputs)
#define BB 8
#define QQ 30
#define DD 1500
#define EE 768
#define KK 11
#define WW 736      // (1500-30)/2 + 1
#define WIN 30
#define STR 2

#define ESPL 8      // E split count (grid)
#define ECH 96      // e per split
#define SC 32       // e sub-chunk staged in LDS
#define DT 256      // d-tile per block
#define NDSUP 6     // ceil(1500/256)
#define DPAD 257    // dsT row stride (words): 257 mod 32 = 1 -> conflict-free
#define QPAD 36     // qs row stride (words): 144B, b128-aligned

// ---------------------------------------------------------------------------
// Kernel 1: normalize q rows (240 rows): qn = qe / max(||qe||, 1e-13)
// ---------------------------------------------------------------------------
__global__ __launch_bounds__(256) void skl_normq(
    const float* __restrict__ qe, float* __restrict__ qn)
{
    int wid = threadIdx.x >> 6, lane = threadIdx.x & 63;
    int row = blockIdx.x * 4 + wid;
    if (row >= BB * QQ) return;
    const float4* p = (const float4*)(qe + (size_t)row * EE);
    float4 v[3];
    float ss = 0.f;
    #pragma unroll
    for (int k = 0; k < 3; k++) {
        v[k] = p[lane + 64 * k];
        ss += v[k].x * v[k].x + v[k].y * v[k].y + v[k].z * v[k].z + v[k].w * v[k].w;
    }
    #pragma unroll
    for (int off = 32; off >= 1; off >>= 1) ss += __shfl_xor(ss, off);
    float inv = 1.f / fmaxf(sqrtf(ss), 1e-13f);
    float4* o = (float4*)(qn + (size_t)row * EE);
    #pragma unroll
    for (int k = 0; k < 3; k++) {
        float4 w = v[k];
        w.x *= inv; w.y *= inv; w.z *= inv; w.w *= inv;
        o[lane + 64 * k] = w;
    }
}

// ---------------------------------------------------------------------------
// Kernel 2 (v3): cos partials, LDS-tiled GEMM.
// Block: 30 q x 256 d x 96 e. Thread: 15 q x 2 d = 30 acc.
// d staged transposed dsT[e][257] (conflict-free both ways); q staged
// qs[30][36] (b128 rows). Also accumulates per-d ssq partials.
// grid = (6 d-supertiles, 8 e-chunks, 8 batches)
// ---------------------------------------------------------------------------
__global__ __launch_bounds__(256) void skl_cos(
    const float* __restrict__ de,     // [8][1500][768]
    const float* __restrict__ qn,     // [240][768] normalized
    float* __restrict__ cpart,        // [8][240][1500]
    float* __restrict__ dssq)         // [8][8][1500]
{
    __shared__ float dsT[SC][DPAD];   // 32.9 KB
    __shared__ float qs[QQ][QPAD];    // 4.3 KB
    int tid = threadIdx.x;
    int dsup = blockIdx.x;   // 0..5
    int ec   = blockIdx.y;   // 0..7
    int b    = blockIdx.z;   // 0..7
    int dbase = dsup * DT;
    int qh    = tid >> 7;    // 0..1 -> q rows qh*15..qh*15+14
    int dslot = tid & 127;   // d = dbase+dslot and dbase+dslot+128
    int e0blk = ec * ECH;

    float acc[15][2];
    #pragma unroll
    for (int q = 0; q < 15; q++) { acc[q][0] = 0.f; acc[q][1] = 0.f; }
    float ssq0 = 0.f, ssq1 = 0.f;

    for (int sc = 0; sc < 3; sc++) {
        int e0 = e0blk + sc * SC;
        __syncthreads();   // previous sub-chunk's readers done
        // stage d tile: 256 d x 8 float4; f = tid + k*256; e4=f&7, dd=f>>3
        // global: 8 consecutive lanes read 128B of one d-row (coalesced)
        // LDS: banks (4*e4+j + dd) mod 32 -> spread, ~conflict-free
        #pragma unroll
        for (int k = 0; k < 8; k++) {
            int f = tid + k * 256;
            int e4 = f & 7, dd = f >> 3;
            int drow = min(dbase + dd, DD - 1);
            float4 v = *(const float4*)(de + ((size_t)b * DD + drow) * EE + e0 + e4 * 4);
            dsT[e4 * 4 + 0][dd] = v.x;
            dsT[e4 * 4 + 1][dd] = v.y;
            dsT[e4 * 4 + 2][dd] = v.z;
            dsT[e4 * 4 + 3][dd] = v.w;
        }
        // stage q tile: 30 rows x 8 float4 = 240 threads
        if (tid < 240) {
            int qrow = tid >> 3, e4 = tid & 7;
            float4 v = *(const float4*)(qn + ((size_t)(b * QQ + qrow)) * EE + e0 + e4 * 4);
            *(float4*)&qs[qrow][e4 * 4] = v;
        }
        __syncthreads();
        #pragma unroll
        for (int e4 = 0; e4 < 8; e4++) {
            float d0v[4], d1v[4];
            #pragma unroll
            for (int j = 0; j < 4; j++) {
                d0v[j] = dsT[e4 * 4 + j][dslot];
                d1v[j] = dsT[e4 * 4 + j][dslot + 128];
            }
            if (qh == 0) {
                #pragma unroll
                for (int j = 0; j < 4; j++) {
                    ssq0 += d0v[j] * d0v[j];
                    ssq1 += d1v[j] * d1v[j];
                }
            }
            #pragma unroll
            for (int q = 0; q < 15; q++) {
                float4 qv = *(const float4*)&qs[qh * 15 + q][e4 * 4];
                acc[q][0] += qv.x * d0v[0] + qv.y * d0v[1] + qv.z * d0v[2] + qv.w * d0v[3];
                acc[q][1] += qv.x * d1v[0] + qv.y * d1v[1] + qv.z * d1v[2] + qv.w * d1v[3];
            }
        }
    }

    int d0 = dbase + dslot, d1 = d0 + 128;
    int qb = b * QQ + qh * 15;
    #pragma unroll
    for (int q = 0; q < 15; q++) {
        if (d0 < DD) cpart[((size_t)ec * BB * QQ + qb + q) * DD + d0] = acc[q][0];
        if (d1 < DD) cpart[((size_t)ec * BB * QQ + qb + q) * DD + d1] = acc[q][1];
    }
    if (qh == 0) {
        if (d0 < DD) dssq[((size_t)ec * BB + b) * DD + d0] = ssq0;
        if (d1 < DD) dssq[((size_t)ec * BB + b) * DD + d1] = ssq1;
    }
}

// ---------------------------------------------------------------------------
// Kernel 3: sum cos partials, invd inline, RBF (f32 __expf) -> window sums
// (f32, float2 LDS reads) -> saturation (f32 fast pow) -> dense_w.
// Block per (b,q,chunk of 256 windows).
// ---------------------------------------------------------------------------
#define DCH 544    // max d-extent a chunk needs (2*255+29+1 = 540, padded)

__global__ __launch_bounds__(256) void skl_windows(
    const float* __restrict__ cpart,   // [8][240][1500]
    const float* __restrict__ dssq,    // [8][8][1500]
    const float* __restrict__ dmask,   // [8][1500]
    const float* __restrict__ qmask,   // [8][30]
    const float* __restrict__ qidfs,   // [240]
    const float* __restrict__ mu,      // [11]
    const float* __restrict__ sigma,   // [11]
    const float* __restrict__ w1, const float* __restrict__ b1,
    const float* __restrict__ w2, const float* __restrict__ b2,
    const float* __restrict__ w3, const float* __restrict__ b3,
    const float* __restrict__ dw,      // [11]
    float* __restrict__ pscore)        // [240][736]
{
    __shared__ float vf[KK][DCH];      // 23.9 KB
    __shared__ float fl[DCH];          // 2.2 KB

    int bid = blockIdx.x;     // 0..719
    int c  = bid % 3;
    int bq = bid / 3;         // 0..239
    int b  = bq / QQ;
    int tid = threadIdx.x;

    int dbase = 512 * c;
    int dcount = min(540, DD - dbase);
    int w = c * 256 + tid;
    bool active = (w < WW);

    float muL[KK], i2s[KK], dwL[KK];
    #pragma unroll
    for (int k = 0; k < KK; k++) {
        muL[k] = mu[k];
        float s = sigma[k];
        i2s[k] = 1.f / (2.f * s * s);
        dwL[k] = dw[k];
    }
    const float* dm = dmask + (size_t)b * DD + dbase;

    // phase 1: sum e-partials, invd, mask, 11 RBF values per d
    for (int i = tid; i < dcount; i += 256) {
        int dg = dbase + i;
        float s = 0.f, sq = 0.f;
        #pragma unroll
        for (int p = 0; p < ESPL; p++) {
            s  += cpart[((size_t)p * BB * QQ + bq) * DD + dg];
            sq += dssq[((size_t)p * BB + b) * DD + dg];
        }
        float invd = 1.f / fmaxf(sqrtf(sq), 1e-13f);
        float cc = s * invd;
        float m = dm[i];
        float ssum = 0.f;
        #pragma unroll
        for (int k = 0; k < KK; k++) {
            float diff = cc - muL[k];
            float val = __expf(-diff * diff * i2s[k]) * m;
            ssum += val;
            vf[k][i] = val;
        }
        fl[i] = (ssum != 0.f) ? 1.f : 0.f;
    }
    __syncthreads();

    // phase 2: per-window sums + saturation + dense_w
    if (active) {
        int dl = 2 * tid;     // window covers d-pairs tid..tid+14 (8B-aligned)
        float pk[KK];
        #pragma unroll
        for (int k = 0; k < KK; k++) pk[k] = 0.f;
        float lenf = 0.f;
        #pragma unroll
        for (int j2 = 0; j2 < WIN / 2; j2++) {
            float2 f2 = *(const float2*)&fl[dl + 2 * j2];
            lenf += f2.x + f2.y;
            #pragma unroll
            for (int k = 0; k < KK; k++) {
                float2 v2 = *(const float2*)&vf[k][dl + 2 * j2];
                pk[k] += v2.x + v2.y;
            }
        }
        float idf = fmaxf(qidfs[bq], 0.f);
        float sat1 = idf * w1[0] + lenf * w1[1] + b1[0];
        float sat2 = 1.f / (idf * w2[0] + lenf * w2[1] + b2[0]);
        float sat3 = idf * w3[0] + lenf * w3[1] + b3[0];
        float mult = qmask[bq] * (lenf > 0.f ? 1.f : 0.f);

        float acc = 0.f;
        #pragma unroll
        for (int k = 0; k < KK; k++) {
            float x = fmaxf(pk[k], 1e-10f);
            float p = exp2f(sat2 * __log2f(x));
            acc += (sat1 * p - sat3) * dwL[k];
        }
        pscore[(size_t)bq * WW + w] = acc * mult;
    }
}

// ---------------------------------------------------------------------------
// Kernel 4: per batch: sum over q (256 threads), then single-wave top-3
// argmax + pooling + gather.
// ---------------------------------------------------------------------------
__global__ __launch_bounds__(256) void skl_topk(
    const float* __restrict__ pscore,  // [240][736]
    const float* __restrict__ chunk,   // [15]
    float* __restrict__ out)           // [8]
{
    __shared__ float s0[WW];
    int b = blockIdx.x;
    int tid = threadIdx.x;

    for (int w = tid; w < WW; w += 256) {
        float s = 0.f;
        for (int q = 0; q < QQ; q++) s += pscore[(size_t)(b * QQ + q) * WW + w];
        s0[w] = (s == 0.f) ? -9900.f : s;
    }
    __syncthreads();

    if (tid < 64) {
        int lane = tid;
        float m[12];
        #pragma unroll
        for (int r = 0; r < 12; r++) {
            int w = lane + 64 * r;
            m[r] = (w < WW) ? s0[w] : -3.3e38f;
        }

        int best[3];
        for (int c = 0; c < 3; c++) {
            float bv = -3.3e38f;
            int bi = 1 << 30;
            #pragma unroll
            for (int r = 0; r < 12; r++) {
                int w = lane + 64 * r;
                if (w < WW && m[r] > bv) { bv = m[r]; bi = w; }
            }
            #pragma unroll
            for (int off = 32; off >= 1; off >>= 1) {
                float ov = __shfl_down(bv, off);
                int oi = __shfl_down(bi, off);
                if (ov > bv || (ov == bv && oi < bi)) { bv = ov; bi = oi; }
            }
            bi = __shfl(bi, 0);
            best[c] = bi;
            float pen = -10001.f - (float)c;
            #pragma unroll
            for (int r = 0; r < 12; r++) {
                int w = lane + 64 * r;
                int dd = w - bi; if (dd < 0) dd = -dd;
                if (w < WW && dd < 15) m[r] = pen;
            }
        }

        float contrib = 0.f;
        if (lane < 15) {
            int c = lane % 3;
            int g = lane / 3;
            const int offs[5] = {0, -1, 1, -2, 2};
            int nb = best[c] + offs[g];
            nb = min(max(nb, 0), WW - 1);
            float v = s0[nb];
            if (v <= -9900.f) v = 0.f;
            contrib = v * chunk[lane];
        }
        #pragma unroll
        for (int off = 32; off >= 1; off >>= 1) contrib += __shfl_down(contrib, off);
        if (lane == 0) out[b] = contrib;
    }
}

// ---------------------------------------------------------------------------
extern "C" void kernel_launch(void* const* d_in, const int* in_sizes, int n_in,
                              void* d_out, int out_size, void* d_ws, size_t ws_size,
                              hipStream_t stream) {
    const float* qe    = (const float*)d_in[0];   // (8,30,768)
    const float* de    = (const float*)d_in[1];   // (8,1500,768)
    const float* qmask = (const float*)d_in[2];   // (8,30)
    const float* dmask = (const float*)d_in[3];   // (8,1500)
    const float* qidfs = (const float*)d_in[4];   // (8,30,1)
    // d_in[5] = document_idfs (unused by reference)
    const float* mu    = (const float*)d_in[6];   // (11,)
    const float* sigma = (const float*)d_in[7];   // (11,)
    const float* w1    = (const float*)d_in[8];
    const float* b1    = (const float*)d_in[9];
    const float* w2    = (const float*)d_in[10];
    const float* b2    = (const float*)d_in[11];
    const float* w3    = (const float*)d_in[12];
    const float* b3    = (const float*)d_in[13];
    const float* dw    = (const float*)d_in[14];  // (1,11)
    const float* chunk = (const float*)d_in[15];  // (1,15)
    float* out = (float*)d_out;

    float* ws = (float*)d_ws;
    float* cpart  = ws;                    // 8*240*1500 = 2,880,000
    float* dssq   = ws + 2880000;          // 8*8*1500   =    96,000
    float* qn     = ws + 2976000;          // 240*768    =   184,320
    float* pscore = ws + 3160320;          // 240*736    =   176,640  (~13.3MB)

    skl_normq<<<60, 256, 0, stream>>>(qe, qn);
    skl_cos<<<dim3(NDSUP, ESPL, BB), 256, 0, stream>>>(de, qn, cpart, dssq);
    skl_windows<<<BB * QQ * 3, 256, 0, stream>>>(cpart, dssq, dmask, qmask, qidfs,
                                                 mu, sigma, w1, b1, w2, b2, w3, b3,
                                                 dw, pscore);
    skl_topk<<<BB, 256, 0, stream>>>(pscore, chunk, out);
}